// Round 1
// baseline (336.494 us; speedup 1.0000x reference)
//
#include <hip/hip_runtime.h>
#include <hip/hip_bf16.h>
#include <stdint.h>

// Problem constants
constexpr int IN_DIM   = 2048;
constexpr int OUT_DIM  = 2048;
constexpr int BATCH    = 4096;
constexpr int KDIM     = 2 * IN_DIM;   // concatenated K: [xn | S] vs [scale_base | Wd]
constexpr float LN_EPS = 1e-5f;

#define TILE 128
#define BK   32

typedef __attribute__((ext_vector_type(8))) short  short8;  // 8 x bf16 (4 VGPRs)
typedef __attribute__((ext_vector_type(4))) float  f32x4;   // MFMA accumulator

__device__ __forceinline__ unsigned short f2bf(float f) {
  __hip_bfloat16 h = __float2bfloat16(f);
  return *reinterpret_cast<unsigned short*>(&h);
}

// ---------------------------------------------------------------------------
// Kernel 1: LayerNorm + RBF basis-sum. One block (256 thr) per batch row.
// Writes bf16 A = [xn | S] row-major (BATCH x KDIM).
// ---------------------------------------------------------------------------
__global__ __launch_bounds__(256) void ln_rbf_kernel(
    const float* __restrict__ x, const float* __restrict__ lnw,
    const float* __restrict__ lnb, const float* __restrict__ betap,
    const float* __restrict__ grid, unsigned short* __restrict__ A)
{
  const int row = blockIdx.x;
  const int tid = threadIdx.x;
  const float4* xr = reinterpret_cast<const float4*>(x + (size_t)row * IN_DIM);
  float4 v0 = xr[tid];
  float4 v1 = xr[tid + 256];
  float s = (v0.x + v0.y) + (v0.z + v0.w) + (v1.x + v1.y) + (v1.z + v1.w);
  float q = v0.x * v0.x + v0.y * v0.y + v0.z * v0.z + v0.w * v0.w
          + v1.x * v1.x + v1.y * v1.y + v1.z * v1.z + v1.w * v1.w;
  #pragma unroll
  for (int off = 32; off > 0; off >>= 1) {
    s += __shfl_down(s, off, 64);
    q += __shfl_down(q, off, 64);
  }
  __shared__ float red[10];
  const int lane = tid & 63, wv = tid >> 6;
  if (lane == 0) { red[wv] = s; red[4 + wv] = q; }
  __syncthreads();
  if (tid == 0) {
    float ts = (red[0] + red[1]) + (red[2] + red[3]);
    float tq = (red[4] + red[5]) + (red[6] + red[7]);
    float mu  = ts * (1.0f / IN_DIM);
    float var = tq * (1.0f / IN_DIM) - mu * mu;
    red[8] = mu;
    red[9] = rsqrtf(var + LN_EPS);
  }
  __syncthreads();
  const float mu = red[8], rs = red[9];
  const float beta = fminf(fmaxf(betap[0], 0.5f), 6.0f);
  float g[8];
  #pragma unroll
  for (int i = 0; i < 8; i++) g[i] = grid[i];
  const float4* w4 = reinterpret_cast<const float4*>(lnw);
  const float4* b4 = reinterpret_cast<const float4*>(lnb);
  unsigned short* Ar = A + (size_t)row * KDIM;
  #pragma unroll
  for (int h = 0; h < 2; h++) {
    const int idx = tid + h * 256;        // float4 index within the row
    float4 xv  = (h == 0) ? v0 : v1;
    float4 wv4 = w4[idx];
    float4 bv4 = b4[idx];
    float xa[4] = {xv.x, xv.y, xv.z, xv.w};
    float wa[4] = {wv4.x, wv4.y, wv4.z, wv4.w};
    float ba[4] = {bv4.x, bv4.y, bv4.z, bv4.w};
    float xn[4], S[4];
    #pragma unroll
    for (int c = 0; c < 4; c++) {
      float xnv = (xa[c] - mu) * rs * wa[c] + ba[c];
      xn[c] = xnv;
      float acc = 0.f;
      #pragma unroll
      for (int gg = 0; gg < 8; gg++) {
        float d = xnv - g[gg];
        acc += __expf(-beta * d * d);
      }
      S[c] = acc;
    }
    uint2 px, ps;
    px.x = (unsigned)f2bf(xn[0]) | ((unsigned)f2bf(xn[1]) << 16);
    px.y = (unsigned)f2bf(xn[2]) | ((unsigned)f2bf(xn[3]) << 16);
    ps.x = (unsigned)f2bf(S[0])  | ((unsigned)f2bf(S[1])  << 16);
    ps.y = (unsigned)f2bf(S[2])  | ((unsigned)f2bf(S[3])  << 16);
    *reinterpret_cast<uint2*>(Ar + idx * 4) = px;
    *reinterpret_cast<uint2*>(Ar + IN_DIM + idx * 4) = ps;
  }
}

// ---------------------------------------------------------------------------
// Kernel 2: Wd[o,i] = sum_g spline_weight[o,i,g]; pack bf16 B = [scale_base | Wd]
// (OUT_DIM x KDIM). One thread per (o, pair-of-i).
// ---------------------------------------------------------------------------
__global__ __launch_bounds__(256) void pack_b_kernel(
    const float* __restrict__ sw, const float* __restrict__ sb,
    unsigned short* __restrict__ B)
{
  const int t  = blockIdx.x * 256 + threadIdx.x;  // [0, OUT_DIM*IN_DIM/2)
  const int o  = t >> 10;                         // IN_DIM/2 = 1024 pairs per row
  const int i0 = (t & 1023) * 2;
  // scale_base -> bf16
  float2 sv = *reinterpret_cast<const float2*>(sb + (size_t)o * IN_DIM + i0);
  unsigned u0 = (unsigned)f2bf(sv.x) | ((unsigned)f2bf(sv.y) << 16);
  *reinterpret_cast<unsigned*>(B + (size_t)o * KDIM + i0) = u0;
  // spline_weight g-reduction (8 contiguous floats per (o,i))
  const float4* sp = reinterpret_cast<const float4*>(sw + ((size_t)o * IN_DIM + i0) * 8);
  float4 a0 = sp[0], a1 = sp[1], a2 = sp[2], a3 = sp[3];
  float s0 = ((a0.x + a0.y) + (a0.z + a0.w)) + ((a1.x + a1.y) + (a1.z + a1.w));
  float s1 = ((a2.x + a2.y) + (a2.z + a2.w)) + ((a3.x + a3.y) + (a3.z + a3.w));
  unsigned u1 = (unsigned)f2bf(s0) | ((unsigned)f2bf(s1) << 16);
  *reinterpret_cast<unsigned*>(B + (size_t)o * KDIM + IN_DIM + i0) = u1;
}

// ---------------------------------------------------------------------------
// Kernel 3: C = A @ B^T + bias.  M=BATCH, N=OUT_DIM, K=KDIM, bf16 MFMA.
// m97 structure: 128x128 tile, BK=32, 256 thr (4 waves, 2x2 of 64x64),
// global_load_lds width=16 staging, 16x16x32 MFMA 4x4 per wave.
// ---------------------------------------------------------------------------
__device__ __forceinline__ void gld_lds16(const unsigned short* g, unsigned short* l) {
  __builtin_amdgcn_global_load_lds(
      (const __attribute__((address_space(1))) void*)g,
      (__attribute__((address_space(3))) void*)l, 16, 0, 0);
}

__global__ __launch_bounds__(256) void gemm_kernel(
    const unsigned short* __restrict__ A, const unsigned short* __restrict__ Bm,
    const float* __restrict__ bias, float* __restrict__ out)
{
  __shared__ __align__(16) unsigned short As[TILE * BK];
  __shared__ __align__(16) unsigned short Bs[TILE * BK];
  const int tid  = threadIdx.x;
  const int lane = tid & 63;
  const int wv   = tid >> 6;
  const int wr   = wv >> 1;        // 2x2 wave grid over the 128x128 tile
  const int wc   = wv & 1;
  const int m0   = blockIdx.y * TILE;
  const int n0   = blockIdx.x * TILE;
  const int lrow = lane & 15;      // A/B fragment row index (m / n)
  const int lk   = (lane >> 4) * 8;// fragment k offset

  f32x4 acc[4][4] = {};

  // Staging segment mapping: seg s in [0,512): row=s>>2, col=(s&3)*8 elems.
  // LDS dest for global_load_lds must be wave-uniform base (+ lane*16 by HW).
  const int seg0 = tid;            // wv*64 + lane
  const int r0 = seg0 >> 2, c0 = (seg0 & 3) * 8;
  const int seg1 = 256 + seg0;
  const int r1 = seg1 >> 2, c1 = (seg1 & 3) * 8;
  unsigned short* ldsA0 = &As[(wv * 64) * 8];
  unsigned short* ldsA1 = &As[(256 + wv * 64) * 8];
  unsigned short* ldsB0 = &Bs[(wv * 64) * 8];
  unsigned short* ldsB1 = &Bs[(256 + wv * 64) * 8];
  const unsigned short* Ab = A  + (size_t)(m0 + r0) * KDIM + c0;
  const unsigned short* Ab1= A  + (size_t)(m0 + r1) * KDIM + c1;
  const unsigned short* Bb = Bm + (size_t)(n0 + r0) * KDIM + c0;
  const unsigned short* Bb1= Bm + (size_t)(n0 + r1) * KDIM + c1;

  for (int k0 = 0; k0 < KDIM; k0 += BK) {
    __syncthreads();               // previous iter's LDS reads done
    gld_lds16(Ab  + k0, ldsA0);
    gld_lds16(Ab1 + k0, ldsA1);
    gld_lds16(Bb  + k0, ldsB0);
    gld_lds16(Bb1 + k0, ldsB1);
    __syncthreads();               // compiler drains vmcnt before barrier

    short8 af[4], bf[4];
    #pragma unroll
    for (int mi = 0; mi < 4; mi++)
      af[mi] = *reinterpret_cast<const short8*>(&As[(wr * 64 + mi * 16 + lrow) * BK + lk]);
    #pragma unroll
    for (int ni = 0; ni < 4; ni++)
      bf[ni] = *reinterpret_cast<const short8*>(&Bs[(wc * 64 + ni * 16 + lrow) * BK + lk]);
    #pragma unroll
    for (int mi = 0; mi < 4; mi++)
      #pragma unroll
      for (int ni = 0; ni < 4; ni++)
        acc[mi][ni] = __builtin_amdgcn_mfma_f32_16x16x32_bf16(af[mi], bf[ni], acc[mi][ni], 0, 0, 0);
  }

  // Epilogue: C/D layout col=lane&15, row=(lane>>4)*4+reg  [measured m89/m91]
  const int rb = (lane >> 4) * 4;
  #pragma unroll
  for (int ni = 0; ni < 4; ni++) {
    const int col = n0 + wc * 64 + ni * 16 + lrow;
    const float bv = bias[col];
    #pragma unroll
    for (int mi = 0; mi < 4; mi++) {
      const int rowm = m0 + wr * 64 + mi * 16 + rb;
      #pragma unroll
      for (int r = 0; r < 4; r++)
        out[(size_t)(rowm + r) * OUT_DIM + col] = acc[mi][ni][r] + bv;
    }
  }
}

// ---------------------------------------------------------------------------
extern "C" void kernel_launch(void* const* d_in, const int* in_sizes, int n_in,
                              void* d_out, int out_size, void* d_ws, size_t ws_size,
                              hipStream_t stream) {
  const float* x    = (const float*)d_in[0];
  const float* lnw  = (const float*)d_in[1];
  const float* lnb  = (const float*)d_in[2];
  const float* sw   = (const float*)d_in[3];   // (OUT, IN, 8)
  const float* sb   = (const float*)d_in[4];   // (OUT, IN)
  const float* bias = (const float*)d_in[5];   // (OUT,)
  const float* beta = (const float*)d_in[6];   // (1,)
  const float* grid = (const float*)d_in[7];   // (8,)
  float* out = (float*)d_out;

  unsigned short* A = (unsigned short*)d_ws;               // BATCH x KDIM bf16 (33.5 MB)
  unsigned short* B = A + (size_t)BATCH * KDIM;            // OUT   x KDIM bf16 (16.8 MB)

  hipLaunchKernelGGL(ln_rbf_kernel, dim3(BATCH), dim3(256), 0, stream,
                     x, lnw, lnb, beta, grid, A);
  hipLaunchKernelGGL(pack_b_kernel, dim3((OUT_DIM * (IN_DIM / 2)) / 256), dim3(256), 0, stream,
                     sw, sb, B);
  hipLaunchKernelGGL(gemm_kernel, dim3(OUT_DIM / TILE, BATCH / TILE), dim3(256), 0, stream,
                     A, B, bias, out);
}

// Round 2
// 316.756 us; speedup vs baseline: 1.0623x; 1.0623x over previous
//
#include <hip/hip_runtime.h>
#include <hip/hip_bf16.h>
#include <stdint.h>

// Problem constants
constexpr int IN_DIM   = 2048;
constexpr int OUT_DIM  = 2048;
constexpr int BATCH    = 4096;
constexpr int KDIM     = 2 * IN_DIM;   // concatenated K: [xn | S] vs [scale_base | Wd]
constexpr float LN_EPS = 1e-5f;

#define TILE 128
#define BK   64

typedef __attribute__((ext_vector_type(8))) short  short8;  // 8 x bf16 (4 VGPRs)
typedef __attribute__((ext_vector_type(4))) float  f32x4;   // MFMA accumulator

__device__ __forceinline__ unsigned short f2bf(float f) {
  __hip_bfloat16 h = __float2bfloat16(f);
  return *reinterpret_cast<unsigned short*>(&h);
}
__device__ __forceinline__ unsigned pack2bf(float a, float b) {
  return (unsigned)f2bf(a) | ((unsigned)f2bf(b) << 16);
}

// ---------------------------------------------------------------------------
// Kernel 1: LayerNorm + RBF basis-sum. One block (256 thr) per batch row.
// Writes bf16 A = [xn | S] row-major (BATCH x KDIM).
// ---------------------------------------------------------------------------
__global__ __launch_bounds__(256) void ln_rbf_kernel(
    const float* __restrict__ x, const float* __restrict__ lnw,
    const float* __restrict__ lnb, const float* __restrict__ betap,
    const float* __restrict__ grid, unsigned short* __restrict__ A)
{
  const int row = blockIdx.x;
  const int tid = threadIdx.x;
  const float4* xr = reinterpret_cast<const float4*>(x + (size_t)row * IN_DIM);
  float4 v0 = xr[tid];
  float4 v1 = xr[tid + 256];
  float s = (v0.x + v0.y) + (v0.z + v0.w) + (v1.x + v1.y) + (v1.z + v1.w);
  float q = v0.x * v0.x + v0.y * v0.y + v0.z * v0.z + v0.w * v0.w
          + v1.x * v1.x + v1.y * v1.y + v1.z * v1.z + v1.w * v1.w;
  #pragma unroll
  for (int off = 32; off > 0; off >>= 1) {
    s += __shfl_down(s, off, 64);
    q += __shfl_down(q, off, 64);
  }
  __shared__ float red[10];
  const int lane = tid & 63, wv = tid >> 6;
  if (lane == 0) { red[wv] = s; red[4 + wv] = q; }
  __syncthreads();
  if (tid == 0) {
    float ts = (red[0] + red[1]) + (red[2] + red[3]);
    float tq = (red[4] + red[5]) + (red[6] + red[7]);
    float mu  = ts * (1.0f / IN_DIM);
    float var = tq * (1.0f / IN_DIM) - mu * mu;
    red[8] = mu;
    red[9] = rsqrtf(var + LN_EPS);
  }
  __syncthreads();
  const float mu = red[8], rs = red[9];
  const float beta = fminf(fmaxf(betap[0], 0.5f), 6.0f);
  float g[8];
  #pragma unroll
  for (int i = 0; i < 8; i++) g[i] = grid[i];
  const float4* w4 = reinterpret_cast<const float4*>(lnw);
  const float4* b4 = reinterpret_cast<const float4*>(lnb);
  unsigned short* Ar = A + (size_t)row * KDIM;
  #pragma unroll
  for (int h = 0; h < 2; h++) {
    const int idx = tid + h * 256;        // float4 index within the row
    float4 xv  = (h == 0) ? v0 : v1;
    float4 wv4 = w4[idx];
    float4 bv4 = b4[idx];
    float xa[4] = {xv.x, xv.y, xv.z, xv.w};
    float wa[4] = {wv4.x, wv4.y, wv4.z, wv4.w};
    float ba[4] = {bv4.x, bv4.y, bv4.z, bv4.w};
    float xn[4], S[4];
    #pragma unroll
    for (int c = 0; c < 4; c++) {
      float xnv = (xa[c] - mu) * rs * wa[c] + ba[c];
      xn[c] = xnv;
      float acc = 0.f;
      #pragma unroll
      for (int gg = 0; gg < 8; gg++) {
        float d = xnv - g[gg];
        acc += __expf(-beta * d * d);
      }
      S[c] = acc;
    }
    uint2 px, ps;
    px.x = pack2bf(xn[0], xn[1]);
    px.y = pack2bf(xn[2], xn[3]);
    ps.x = pack2bf(S[0], S[1]);
    ps.y = pack2bf(S[2], S[3]);
    *reinterpret_cast<uint2*>(Ar + idx * 4) = px;
    *reinterpret_cast<uint2*>(Ar + IN_DIM + idx * 4) = ps;
  }
}

// ---------------------------------------------------------------------------
// Kernel 2: pack bf16 B = [scale_base | Wd], Wd[o,i] = sum_g spline_weight.
// Fully-coalesced: one float4 per lane, shfl_xor/shfl_down g-reduction.
// Branch is block-uniform (sw part: blocks [0, 32768); sb part after).
// ---------------------------------------------------------------------------
constexpr int SW_F4   = OUT_DIM * IN_DIM * 2;   // float4 count of spline_weight
constexpr int SB_F4   = OUT_DIM * IN_DIM / 4;   // float4 count of scale_base

__global__ __launch_bounds__(256) void pack_b_kernel(
    const float* __restrict__ sw, const float* __restrict__ sb,
    unsigned* __restrict__ Bu)    // B as uint (2 bf16 per uint), OUT x KDIM/2
{
  const int g = blockIdx.x * 256 + threadIdx.x;
  const int lane = threadIdx.x & 63;
  if (g < SW_F4) {
    float4 v = reinterpret_cast<const float4*>(sw)[g];
    float s = (v.x + v.y) + (v.z + v.w);
    s += __shfl_xor(s, 1, 64);                 // full Wd[i] in both lanes of pair
    float hi = __shfl_down(s, 2, 64);          // Wd of i+1 for even-pair lanes
    if ((lane & 3) == 0) {
      const int i_lin = g >> 1;                // linear (o,i)
      const int o = i_lin >> 11;               // / IN_DIM
      const int i = i_lin & (IN_DIM - 1);
      Bu[(size_t)o * (KDIM / 2) + (IN_DIM / 2) + (i >> 1)] = pack2bf(s, hi);
    }
  } else {
    const int t = g - SW_F4;                   // [0, SB_F4)
    float4 v = reinterpret_cast<const float4*>(sb)[t];
    const int o  = t >> 9;                     // 512 float4 per sb row
    const int i4 = t & 511;
    uint2 u;
    u.x = pack2bf(v.x, v.y);
    u.y = pack2bf(v.z, v.w);
    *reinterpret_cast<uint2*>(&Bu[(size_t)o * (KDIM / 2) + i4 * 2]) = u;
  }
}

// ---------------------------------------------------------------------------
// Kernel 3: C = A @ B^T + bias.  M=BATCH, N=OUT_DIM, K=KDIM, bf16 MFMA.
// 128x128 tile, BK=64 (half the barrier drains of BK=32), 256 thr / 4 waves
// (2x2 of 64x64), global_load_lds width=16, XOR-swizzled LDS columns
// (swizzle folded into the GLOBAL fetch address — global_load_lds cannot
// scatter; LDS dest is wave-uniform base + lane*16 [m104/m108]).
// Logical (row, col8) stored at LDS slot row*8 + (col8 ^ (row & 7)).
// ---------------------------------------------------------------------------
__device__ __forceinline__ void gld_lds16(const unsigned short* g, unsigned short* l) {
  __builtin_amdgcn_global_load_lds(
      (const __attribute__((address_space(1))) void*)g,
      (__attribute__((address_space(3))) void*)l, 16, 0, 0);
}

__global__ __launch_bounds__(256) void gemm_kernel(
    const unsigned short* __restrict__ A, const unsigned short* __restrict__ Bm,
    const float* __restrict__ bias, float* __restrict__ out)
{
  __shared__ __align__(16) unsigned short As[TILE * BK];   // 16 KB
  __shared__ __align__(16) unsigned short Bs[TILE * BK];   // 16 KB
  const int tid  = threadIdx.x;
  const int lane = tid & 63;
  const int wv   = tid >> 6;
  const int wr   = wv >> 1;        // 2x2 wave grid over the 128x128 tile
  const int wc   = wv & 1;
  const int m0   = blockIdx.y * TILE;
  const int n0   = blockIdx.x * TILE;
  const int lrow = lane & 15;      // fragment m / n index
  const int lkq  = lane >> 4;      // k-quarter within a 16-B-granule row

  f32x4 acc[4][4] = {};

  // Staging: 1024 16-B segments per matrix per iter; seg s -> LDS slot s;
  // slot (row = s>>3, col8' = s&7) holds global col8 = col8' ^ (row&7).
  const unsigned short* Ap[4];
  const unsigned short* Bp[4];
  unsigned short* ldsA[4];
  unsigned short* ldsB[4];
  #pragma unroll
  for (int j = 0; j < 4; j++) {
    const int seg  = j * 256 + wv * 64 + lane;
    const int row  = seg >> 3;
    const int gcol = ((seg & 7) ^ (row & 7)) * 8;
    Ap[j] = A  + (size_t)(m0 + row) * KDIM + gcol;
    Bp[j] = Bm + (size_t)(n0 + row) * KDIM + gcol;
    ldsA[j] = &As[(j * 256 + wv * 64) * 8];
    ldsB[j] = &Bs[(j * 256 + wv * 64) * 8];
  }

  for (int k0 = 0; k0 < KDIM; k0 += BK) {
    __syncthreads();               // previous iter's LDS reads done
    #pragma unroll
    for (int j = 0; j < 4; j++) gld_lds16(Ap[j] + k0, ldsA[j]);
    #pragma unroll
    for (int j = 0; j < 4; j++) gld_lds16(Bp[j] + k0, ldsB[j]);
    __syncthreads();               // drains vmcnt before barrier

    short8 af[2][4], bf[2][4];
    #pragma unroll
    for (int h = 0; h < 2; h++) {
      #pragma unroll
      for (int mi = 0; mi < 4; mi++) {
        const int r = wr * 64 + mi * 16 + lrow;
        af[h][mi] = *reinterpret_cast<const short8*>(
            &As[r * BK + (((h << 2) | lkq) ^ (lrow & 7)) * 8]);
      }
      #pragma unroll
      for (int ni = 0; ni < 4; ni++) {
        const int r = wc * 64 + ni * 16 + lrow;
        bf[h][ni] = *reinterpret_cast<const short8*>(
            &Bs[r * BK + (((h << 2) | lkq) ^ (lrow & 7)) * 8]);
      }
    }
    #pragma unroll
    for (int h = 0; h < 2; h++)
      #pragma unroll
      for (int mi = 0; mi < 4; mi++)
        #pragma unroll
        for (int ni = 0; ni < 4; ni++)
          acc[mi][ni] = __builtin_amdgcn_mfma_f32_16x16x32_bf16(
              af[h][mi], bf[h][ni], acc[mi][ni], 0, 0, 0);
  }

  // Epilogue: C/D layout col=lane&15, row=(lane>>4)*4+reg  [measured m89/m91]
  const int rb = (lane >> 4) * 4;
  #pragma unroll
  for (int ni = 0; ni < 4; ni++) {
    const int col = n0 + wc * 64 + ni * 16 + lrow;
    const float bv = bias[col];
    #pragma unroll
    for (int mi = 0; mi < 4; mi++) {
      const int rowm = m0 + wr * 64 + mi * 16 + rb;
      #pragma unroll
      for (int r = 0; r < 4; r++)
        out[(size_t)(rowm + r) * OUT_DIM + col] = acc[mi][ni][r] + bv;
    }
  }
}

// ---------------------------------------------------------------------------
extern "C" void kernel_launch(void* const* d_in, const int* in_sizes, int n_in,
                              void* d_out, int out_size, void* d_ws, size_t ws_size,
                              hipStream_t stream) {
  const float* x    = (const float*)d_in[0];
  const float* lnw  = (const float*)d_in[1];
  const float* lnb  = (const float*)d_in[2];
  const float* sw   = (const float*)d_in[3];   // (OUT, IN, 8)
  const float* sb   = (const float*)d_in[4];   // (OUT, IN)
  const float* bias = (const float*)d_in[5];   // (OUT,)
  const float* beta = (const float*)d_in[6];   // (1,)
  const float* grid = (const float*)d_in[7];   // (8,)
  float* out = (float*)d_out;

  unsigned short* A = (unsigned short*)d_ws;               // BATCH x KDIM bf16 (33.5 MB)
  unsigned short* B = A + (size_t)BATCH * KDIM;            // OUT   x KDIM bf16 (16.8 MB)

  hipLaunchKernelGGL(ln_rbf_kernel, dim3(BATCH), dim3(256), 0, stream,
                     x, lnw, lnb, beta, grid, A);
  hipLaunchKernelGGL(pack_b_kernel, dim3((SW_F4 + SB_F4) / 256), dim3(256), 0, stream,
                     sw, sb, (unsigned*)B);
  hipLaunchKernelGGL(gemm_kernel, dim3(OUT_DIM / TILE, BATCH / TILE), dim3(256), 0, stream,
                     A, B, bias, out);
}

// Round 3
// 311.931 us; speedup vs baseline: 1.0787x; 1.0155x over previous
//
#include <hip/hip_runtime.h>
#include <hip/hip_bf16.h>
#include <stdint.h>

// Problem constants
constexpr int IN_DIM   = 2048;
constexpr int OUT_DIM  = 2048;
constexpr int BATCH    = 4096;
constexpr int KDIM     = 2 * IN_DIM;   // concatenated K: [xn | S] vs [scale_base | Wd]
constexpr float LN_EPS = 1e-5f;

#define TILE 128
#define BK   64
constexpr int NK    = KDIM / BK;       // 64 k-steps
constexpr int STAGE = TILE * BK;       // shorts per matrix per stage (16 KB)

typedef __attribute__((ext_vector_type(8))) short  short8;  // 8 x bf16 (4 VGPRs)
typedef __attribute__((ext_vector_type(4))) float  f32x4;   // MFMA accumulator

__device__ __forceinline__ unsigned short f2bf(float f) {
  __hip_bfloat16 h = __float2bfloat16(f);
  return *reinterpret_cast<unsigned short*>(&h);
}
__device__ __forceinline__ unsigned pack2bf(float a, float b) {
  return (unsigned)f2bf(a) | ((unsigned)f2bf(b) << 16);
}

// ---------------------------------------------------------------------------
// Kernel 1: LayerNorm + RBF basis-sum. One block (256 thr) per batch row.
// Writes bf16 A = [xn | S] row-major (BATCH x KDIM).
// ---------------------------------------------------------------------------
__global__ __launch_bounds__(256) void ln_rbf_kernel(
    const float* __restrict__ x, const float* __restrict__ lnw,
    const float* __restrict__ lnb, const float* __restrict__ betap,
    const float* __restrict__ grid, unsigned short* __restrict__ A)
{
  const int row = blockIdx.x;
  const int tid = threadIdx.x;
  const float4* xr = reinterpret_cast<const float4*>(x + (size_t)row * IN_DIM);
  float4 v0 = xr[tid];
  float4 v1 = xr[tid + 256];
  float s = (v0.x + v0.y) + (v0.z + v0.w) + (v1.x + v1.y) + (v1.z + v1.w);
  float q = v0.x * v0.x + v0.y * v0.y + v0.z * v0.z + v0.w * v0.w
          + v1.x * v1.x + v1.y * v1.y + v1.z * v1.z + v1.w * v1.w;
  #pragma unroll
  for (int off = 32; off > 0; off >>= 1) {
    s += __shfl_down(s, off, 64);
    q += __shfl_down(q, off, 64);
  }
  __shared__ float red[10];
  const int lane = tid & 63, wv = tid >> 6;
  if (lane == 0) { red[wv] = s; red[4 + wv] = q; }
  __syncthreads();
  if (tid == 0) {
    float ts = (red[0] + red[1]) + (red[2] + red[3]);
    float tq = (red[4] + red[5]) + (red[6] + red[7]);
    float mu  = ts * (1.0f / IN_DIM);
    float var = tq * (1.0f / IN_DIM) - mu * mu;
    red[8] = mu;
    red[9] = rsqrtf(var + LN_EPS);
  }
  __syncthreads();
  const float mu = red[8], rs = red[9];
  const float beta = fminf(fmaxf(betap[0], 0.5f), 6.0f);
  float g[8];
  #pragma unroll
  for (int i = 0; i < 8; i++) g[i] = grid[i];
  const float4* w4 = reinterpret_cast<const float4*>(lnw);
  const float4* b4 = reinterpret_cast<const float4*>(lnb);
  unsigned short* Ar = A + (size_t)row * KDIM;
  #pragma unroll
  for (int h = 0; h < 2; h++) {
    const int idx = tid + h * 256;        // float4 index within the row
    float4 xv  = (h == 0) ? v0 : v1;
    float4 wv4 = w4[idx];
    float4 bv4 = b4[idx];
    float xa[4] = {xv.x, xv.y, xv.z, xv.w};
    float wa[4] = {wv4.x, wv4.y, wv4.z, wv4.w};
    float ba[4] = {bv4.x, bv4.y, bv4.z, bv4.w};
    float xn[4], S[4];
    #pragma unroll
    for (int c = 0; c < 4; c++) {
      float xnv = (xa[c] - mu) * rs * wa[c] + ba[c];
      xn[c] = xnv;
      float acc = 0.f;
      #pragma unroll
      for (int gg = 0; gg < 8; gg++) {
        float d = xnv - g[gg];
        acc += __expf(-beta * d * d);
      }
      S[c] = acc;
    }
    uint2 px, ps;
    px.x = pack2bf(xn[0], xn[1]);
    px.y = pack2bf(xn[2], xn[3]);
    ps.x = pack2bf(S[0], S[1]);
    ps.y = pack2bf(S[2], S[3]);
    *reinterpret_cast<uint2*>(Ar + idx * 4) = px;
    *reinterpret_cast<uint2*>(Ar + IN_DIM + idx * 4) = ps;
  }
}

// ---------------------------------------------------------------------------
// Kernel 2: pack bf16 B = [scale_base | Wd], Wd[o,i] = sum_g spline_weight.
// Fully-coalesced: one float4 per lane, shfl_xor/shfl_down g-reduction.
// ---------------------------------------------------------------------------
constexpr int SW_F4   = OUT_DIM * IN_DIM * 2;   // float4 count of spline_weight
constexpr int SB_F4   = OUT_DIM * IN_DIM / 4;   // float4 count of scale_base

__global__ __launch_bounds__(256) void pack_b_kernel(
    const float* __restrict__ sw, const float* __restrict__ sb,
    unsigned* __restrict__ Bu)    // B as uint (2 bf16 per uint), OUT x KDIM/2
{
  const int g = blockIdx.x * 256 + threadIdx.x;
  const int lane = threadIdx.x & 63;
  if (g < SW_F4) {
    float4 v = reinterpret_cast<const float4*>(sw)[g];
    float s = (v.x + v.y) + (v.z + v.w);
    s += __shfl_xor(s, 1, 64);                 // full Wd[i] in both lanes of pair
    float hi = __shfl_down(s, 2, 64);          // Wd of i+1 for even-pair lanes
    if ((lane & 3) == 0) {
      const int i_lin = g >> 1;                // linear (o,i)
      const int o = i_lin >> 11;               // / IN_DIM
      const int i = i_lin & (IN_DIM - 1);
      Bu[(size_t)o * (KDIM / 2) + (IN_DIM / 2) + (i >> 1)] = pack2bf(s, hi);
    }
  } else {
    const int t = g - SW_F4;                   // [0, SB_F4)
    float4 v = reinterpret_cast<const float4*>(sb)[t];
    const int o  = t >> 9;                     // 512 float4 per sb row
    const int i4 = t & 511;
    uint2 u;
    u.x = pack2bf(v.x, v.y);
    u.y = pack2bf(v.z, v.w);
    *reinterpret_cast<uint2*>(&Bu[(size_t)o * (KDIM / 2) + i4 * 2]) = u;
  }
}

// ---------------------------------------------------------------------------
// Kernel 3: C = A @ B^T + bias.  M=BATCH, N=OUT_DIM, K=KDIM, bf16 MFMA.
// 128x128 tile, BK=64, 256 thr / 4 waves (2x2 of 64x64), XOR-swizzled LDS,
// global_load_lds width=16, DOUBLE-BUFFERED stages: prefetch stage k+1 into
// the other LDS half right after the barrier, compute stage k. One barrier
// per k-step (64 total); the barrier's vmcnt(0) drain hits loads that aged a
// full compute stage. LDS 64 KB/block x 2 blocks/CU = 128 KB <= 160 KB.
// ---------------------------------------------------------------------------
__device__ __forceinline__ void gld_lds16(const unsigned short* g, unsigned short* l) {
  __builtin_amdgcn_global_load_lds(
      (const __attribute__((address_space(1))) void*)g,
      (__attribute__((address_space(3))) void*)l, 16, 0, 0);
}

__global__ __launch_bounds__(256) void gemm_kernel(
    const unsigned short* __restrict__ A, const unsigned short* __restrict__ Bm,
    const float* __restrict__ bias, float* __restrict__ out)
{
  __shared__ __align__(16) unsigned short As[2 * STAGE];   // 32 KB
  __shared__ __align__(16) unsigned short Bs[2 * STAGE];   // 32 KB
  const int tid  = threadIdx.x;
  const int lane = tid & 63;
  const int wv   = tid >> 6;
  const int wr   = wv >> 1;        // 2x2 wave grid over the 128x128 tile
  const int wc   = wv & 1;
  const int m0   = blockIdx.y * TILE;
  const int n0   = blockIdx.x * TILE;
  const int lrow = lane & 15;      // fragment m / n index
  const int lkq  = lane >> 4;      // k-quarter within a 16-B-granule row

  f32x4 acc[4][4] = {};

  // Staging: 1024 16-B segments per matrix per stage; seg s -> LDS slot s;
  // slot (row = s>>3, col8' = s&7) holds global col8 = col8' ^ (row&7)
  // (swizzle folded into the GLOBAL fetch address; LDS dest is wave-uniform
  // base + lane*16 [m104/m108]).
  const unsigned short* Ap[4];
  const unsigned short* Bp[4];
  unsigned short* ldsA[4];
  unsigned short* ldsB[4];
  #pragma unroll
  for (int j = 0; j < 4; j++) {
    const int seg  = j * 256 + wv * 64 + lane;
    const int row  = seg >> 3;
    const int gcol = ((seg & 7) ^ (row & 7)) * 8;
    Ap[j] = A  + (size_t)(m0 + row) * KDIM + gcol;
    Bp[j] = Bm + (size_t)(n0 + row) * KDIM + gcol;
    ldsA[j] = &As[(j * 256 + wv * 64) * 8];
    ldsB[j] = &Bs[(j * 256 + wv * 64) * 8];
  }

  // Prologue: stage 0 into buffer 0.
  #pragma unroll
  for (int j = 0; j < 4; j++) gld_lds16(Ap[j], ldsA[j]);
  #pragma unroll
  for (int j = 0; j < 4; j++) gld_lds16(Bp[j], ldsB[j]);

  #pragma unroll 1
  for (int kt = 0; kt < NK; kt++) {
    __syncthreads();               // drains stage-kt loads (issued a stage ago)
    const int cur = (kt & 1) * STAGE;
    if (kt + 1 < NK) {             // wave-uniform; prefetch stage kt+1
      const int nxt = ((kt + 1) & 1) * STAGE;
      const int koff = (kt + 1) * BK;
      #pragma unroll
      for (int j = 0; j < 4; j++) gld_lds16(Ap[j] + koff, ldsA[j] + nxt);
      #pragma unroll
      for (int j = 0; j < 4; j++) gld_lds16(Bp[j] + koff, ldsB[j] + nxt);
    }

    short8 af[2][4], bf[2][4];
    #pragma unroll
    for (int h = 0; h < 2; h++) {
      #pragma unroll
      for (int mi = 0; mi < 4; mi++) {
        const int r = wr * 64 + mi * 16 + lrow;
        af[h][mi] = *reinterpret_cast<const short8*>(
            &As[cur + r * BK + (((h << 2) | lkq) ^ (lrow & 7)) * 8]);
      }
      #pragma unroll
      for (int ni = 0; ni < 4; ni++) {
        const int r = wc * 64 + ni * 16 + lrow;
        bf[h][ni] = *reinterpret_cast<const short8*>(
            &Bs[cur + r * BK + (((h << 2) | lkq) ^ (lrow & 7)) * 8]);
      }
    }
    #pragma unroll
    for (int h = 0; h < 2; h++)
      #pragma unroll
      for (int mi = 0; mi < 4; mi++)
        #pragma unroll
        for (int ni = 0; ni < 4; ni++)
          acc[mi][ni] = __builtin_amdgcn_mfma_f32_16x16x32_bf16(
              af[h][mi], bf[h][ni], acc[mi][ni], 0, 0, 0);
  }

  // Epilogue: C/D layout col=lane&15, row=(lane>>4)*4+reg  [measured m89/m91]
  const int rb = (lane >> 4) * 4;
  #pragma unroll
  for (int ni = 0; ni < 4; ni++) {
    const int col = n0 + wc * 64 + ni * 16 + lrow;
    const float bv = bias[col];
    #pragma unroll
    for (int mi = 0; mi < 4; mi++) {
      const int rowm = m0 + wr * 64 + mi * 16 + rb;
      #pragma unroll
      for (int r = 0; r < 4; r++)
        out[(size_t)(rowm + r) * OUT_DIM + col] = acc[mi][ni][r] + bv;
    }
  }
}

// ---------------------------------------------------------------------------
extern "C" void kernel_launch(void* const* d_in, const int* in_sizes, int n_in,
                              void* d_out, int out_size, void* d_ws, size_t ws_size,
                              hipStream_t stream) {
  const float* x    = (const float*)d_in[0];
  const float* lnw  = (const float*)d_in[1];
  const float* lnb  = (const float*)d_in[2];
  const float* sw   = (const float*)d_in[3];   // (OUT, IN, 8)
  const float* sb   = (const float*)d_in[4];   // (OUT, IN)
  const float* bias = (const float*)d_in[5];   // (OUT,)
  const float* beta = (const float*)d_in[6];   // (1,)
  const float* grid = (const float*)d_in[7];   // (8,)
  float* out = (float*)d_out;

  unsigned short* A = (unsigned short*)d_ws;               // BATCH x KDIM bf16 (33.5 MB)
  unsigned short* B = A + (size_t)BATCH * KDIM;            // OUT   x KDIM bf16 (16.8 MB)

  hipLaunchKernelGGL(ln_rbf_kernel, dim3(BATCH), dim3(256), 0, stream,
                     x, lnw, lnb, beta, grid, A);
  hipLaunchKernelGGL(pack_b_kernel, dim3((SW_F4 + SB_F4) / 256), dim3(256), 0, stream,
                     sw, sb, (unsigned*)B);
  hipLaunchKernelGGL(gemm_kernel, dim3(OUT_DIM / TILE, BATCH / TILE), dim3(256), 0, stream,
                     A, B, bias, out);
}